// Round 2
// baseline (813.413 us; speedup 1.0000x reference)
//
#include <hip/hip_runtime.h>
#include <math.h>

// Problem constants (fixed by setup_inputs)
#define BB 4
#define NI 64
#define CC 64
#define HH 256
#define WW 256
#define HW (HH * WW)

// numpy/jax "reflect" (mirror, edge not repeated), pad=1 so i in [-1, n]
__device__ __forceinline__ int refl(int i, int n) {
    i = (i < 0) ? -i : i;
    return (i >= n) ? (2 * n - 2 - i) : i;
}

// 512 threads/block: 256 pixel slots x 2 channel-halves.
// half h accumulates conv partials over ni in [32h, 32h+32); LDS exchange +
// redundant softmax; then half h applies the filter to channels [32h, 32h+32).
__global__ __launch_bounds__(512, 8) void pff_fused2(
    const float* __restrict__ features,
    const float* __restrict__ inpt,
    const float* __restrict__ wgt,
    const float* __restrict__ bias,
    float* __restrict__ out)
{
    __shared__ float part[2][9][260];   // [half][tap][pixel-slot], padded row

    const int tid  = threadIdx.x;
    const int half = tid >> 8;           // wave-uniform (waves 0-3 vs 4-7)
    const int p    = tid & 255;
    const int wx = blockIdx.x * 64 + (p & 63);   // W: 4 strips of 64
    const int hy = blockIdx.y * 4 + (p >> 6);    // H: 64 groups of 4
    const int b  = blockIdx.z;

    const int r0 = refl(hy - 1, HH) * WW;
    const int r1 = hy * WW;
    const int r2 = refl(hy + 1, HH) * WW;
    const int iw0 = refl(wx - 1, WW), iw1 = wx, iw2 = refl(wx + 1, WW);

    float acc[9];
    #pragma unroll
    for (int k = 0; k < 9; ++k) acc[k] = 0.f;

    // ---- Phase 1: conv partials over this half's 32 channels ----
    const float* fb = features + (size_t)b * NI * HW + (size_t)half * 32 * HW;
    const float* wbase = wgt + half * 32 * 9;    // wgt[9][NI][3][3]
    #pragma unroll 2
    for (int ni = 0; ni < 32; ++ni) {
        const float* fc = fb + (size_t)ni * HW;
        float f0 = fc[r0 + iw0], f1 = fc[r0 + iw1], f2 = fc[r0 + iw2];
        float f3 = fc[r1 + iw0], f4 = fc[r1 + iw1], f5 = fc[r1 + iw2];
        float f6 = fc[r2 + iw0], f7 = fc[r2 + iw1], f8 = fc[r2 + iw2];
        const float* wn = wbase + ni * 9;        // wave-uniform -> s_load
        #pragma unroll
        for (int k = 0; k < 9; ++k) {
            const float* wk = wn + k * (NI * 9);
            acc[k] = fmaf(f0, wk[0], acc[k]);
            acc[k] = fmaf(f1, wk[1], acc[k]);
            acc[k] = fmaf(f2, wk[2], acc[k]);
            acc[k] = fmaf(f3, wk[3], acc[k]);
            acc[k] = fmaf(f4, wk[4], acc[k]);
            acc[k] = fmaf(f5, wk[5], acc[k]);
            acc[k] = fmaf(f6, wk[6], acc[k]);
            acc[k] = fmaf(f7, wk[7], acc[k]);
            acc[k] = fmaf(f8, wk[8], acc[k]);
        }
    }

    // ---- exchange partials, combine, softmax (redundant in both halves) ----
    #pragma unroll
    for (int k = 0; k < 9; ++k) part[half][k][p] = acc[k];
    __syncthreads();
    #pragma unroll
    for (int k = 0; k < 9; ++k) acc[k] += part[1 - half][k][p] + bias[k];

    float m = acc[0];
    #pragma unroll
    for (int k = 1; k < 9; ++k) m = fmaxf(m, acc[k]);
    float s = 0.f;
    #pragma unroll
    for (int k = 0; k < 9; ++k) { acc[k] = __expf(acc[k] - m); s += acc[k]; }
    const float inv = 1.f / s;
    #pragma unroll
    for (int k = 0; k < 9; ++k) acc[k] *= inv;

    // ---- Phase 2: apply filter to this half's 32 channels ----
    const float* ib = inpt + (size_t)b * CC * HW + (size_t)half * 32 * HW;
    float* ob       = out  + (size_t)b * CC * HW + (size_t)half * 32 * HW;
    const int opix = r1 + wx;
    #pragma unroll 2
    for (int c = 0; c < 32; ++c) {
        const float* ic = ib + (size_t)c * HW;
        float o = acc[0] * ic[r0 + iw0];
        o = fmaf(acc[1], ic[r0 + iw1], o);
        o = fmaf(acc[2], ic[r0 + iw2], o);
        o = fmaf(acc[3], ic[r1 + iw0], o);
        o = fmaf(acc[4], ic[r1 + iw1], o);
        o = fmaf(acc[5], ic[r1 + iw2], o);
        o = fmaf(acc[6], ic[r2 + iw0], o);
        o = fmaf(acc[7], ic[r2 + iw1], o);
        o = fmaf(acc[8], ic[r2 + iw2], o);
        ob[(size_t)c * HW + opix] = o;
    }
}

extern "C" void kernel_launch(void* const* d_in, const int* in_sizes, int n_in,
                              void* d_out, int out_size, void* d_ws, size_t ws_size,
                              hipStream_t stream) {
    const float* features = (const float*)d_in[0];
    const float* inpt     = (const float*)d_in[1];
    const float* wgt      = (const float*)d_in[2];
    const float* bias     = (const float*)d_in[3];
    float* out            = (float*)d_out;

    dim3 grid(WW / 64, HH / 4, BB);  // (4, 64, 4) = 1024 blocks
    dim3 block(512);
    pff_fused2<<<grid, block, 0, stream>>>(features, inpt, wgt, bias, out);
}

// Round 3
// 187.560 us; speedup vs baseline: 4.3368x; 4.3368x over previous
//
#include <hip/hip_runtime.h>
#include <math.h>

// Problem constants (fixed by setup_inputs)
#define BB 4
#define NI 64
#define CC 64
#define HH 256
#define WW 256
#define HW (HH * WW)

// numpy/jax "reflect" (mirror, edge not repeated), pad=1 so i in [-1, n]
__device__ __forceinline__ int refl(int i, int n) {
    i = (i < 0) ? -i : i;
    return (i >= n) ? (2 * n - 2 - i) : i;
}

// 256 threads/block = 64 pixel slots x 4 channel-quarters (1 wave each).
// Quarter q accumulates conv partials over ni in [16q, 16q+16); LDS combine +
// redundant softmax; then quarter q applies the filter to channels [16q,16q+16).
// No launch-bounds register cap (R2 lesson: cap 64 -> scratch spill, 2.7 GB HBM).
__global__ __launch_bounds__(256) void pff_fused4(
    const float* __restrict__ features,
    const float* __restrict__ inpt,
    const float* __restrict__ wgt,
    const float* __restrict__ bias,
    float* __restrict__ out)
{
    __shared__ float part[4][9][64];     // stride-1 in pixel slot: conflict-free

    const int tid = threadIdx.x;
    const int q   = tid >> 6;            // wave index = channel quarter (uniform)
    const int p   = tid & 63;
    const int wx  = blockIdx.x * 64 + p; // 64 consecutive w per block
    const int hy  = blockIdx.y;
    const int b   = blockIdx.z;

    const int r0 = refl(hy - 1, HH) * WW;
    const int r1 = hy * WW;
    const int r2 = refl(hy + 1, HH) * WW;
    const int iw0 = refl(wx - 1, WW), iw1 = wx, iw2 = refl(wx + 1, WW);

    float acc[9];
    #pragma unroll
    for (int k = 0; k < 9; ++k) acc[k] = 0.f;

    // ---- Phase 1: conv partials over this quarter's 16 channels ----
    const float* fb = features + (size_t)b * NI * HW + (size_t)q * 16 * HW;
    for (int ni = 0; ni < 16; ++ni) {
        const float* fc = fb + (size_t)ni * HW;
        float f0 = fc[r0 + iw0], f1 = fc[r0 + iw1], f2 = fc[r0 + iw2];
        float f3 = fc[r1 + iw0], f4 = fc[r1 + iw1], f5 = fc[r1 + iw2];
        float f6 = fc[r2 + iw0], f7 = fc[r2 + iw1], f8 = fc[r2 + iw2];
        const float* wn = wgt + (q * 16 + ni) * 9;   // wave-uniform -> s_load
        #pragma unroll
        for (int k = 0; k < 9; ++k) {
            const float* wk = wn + k * (NI * 9);     // wgt[9][NI][3][3]
            acc[k] = fmaf(f0, wk[0], acc[k]);
            acc[k] = fmaf(f1, wk[1], acc[k]);
            acc[k] = fmaf(f2, wk[2], acc[k]);
            acc[k] = fmaf(f3, wk[3], acc[k]);
            acc[k] = fmaf(f4, wk[4], acc[k]);
            acc[k] = fmaf(f5, wk[5], acc[k]);
            acc[k] = fmaf(f6, wk[6], acc[k]);
            acc[k] = fmaf(f7, wk[7], acc[k]);
            acc[k] = fmaf(f8, wk[8], acc[k]);
        }
    }

    // ---- combine partials across quarters, softmax (redundant per quarter) ----
    #pragma unroll
    for (int k = 0; k < 9; ++k) part[q][k][p] = acc[k];
    __syncthreads();
    #pragma unroll
    for (int k = 0; k < 9; ++k)
        acc[k] = part[0][k][p] + part[1][k][p] + part[2][k][p] + part[3][k][p]
               + bias[k];

    float m = acc[0];
    #pragma unroll
    for (int k = 1; k < 9; ++k) m = fmaxf(m, acc[k]);
    float s = 0.f;
    #pragma unroll
    for (int k = 0; k < 9; ++k) { acc[k] = __expf(acc[k] - m); s += acc[k]; }
    const float inv = 1.f / s;
    #pragma unroll
    for (int k = 0; k < 9; ++k) acc[k] *= inv;

    // ---- Phase 2: apply filter to this quarter's 16 channels ----
    const float* ib = inpt + (size_t)b * CC * HW + (size_t)q * 16 * HW;
    float* ob       = out  + (size_t)b * CC * HW + (size_t)q * 16 * HW;
    const int opix = r1 + wx;
    for (int c = 0; c < 16; ++c) {
        const float* ic = ib + (size_t)c * HW;
        float o = acc[0] * ic[r0 + iw0];
        o = fmaf(acc[1], ic[r0 + iw1], o);
        o = fmaf(acc[2], ic[r0 + iw2], o);
        o = fmaf(acc[3], ic[r1 + iw0], o);
        o = fmaf(acc[4], ic[r1 + iw1], o);
        o = fmaf(acc[5], ic[r1 + iw2], o);
        o = fmaf(acc[6], ic[r2 + iw0], o);
        o = fmaf(acc[7], ic[r2 + iw1], o);
        o = fmaf(acc[8], ic[r2 + iw2], o);
        ob[(size_t)c * HW + opix] = o;
    }
}

extern "C" void kernel_launch(void* const* d_in, const int* in_sizes, int n_in,
                              void* d_out, int out_size, void* d_ws, size_t ws_size,
                              hipStream_t stream) {
    const float* features = (const float*)d_in[0];
    const float* inpt     = (const float*)d_in[1];
    const float* wgt      = (const float*)d_in[2];
    const float* bias     = (const float*)d_in[3];
    float* out            = (float*)d_out;

    dim3 grid(WW / 64, HH, BB);   // (4, 256, 4) = 4096 blocks, 16384 waves
    dim3 block(256);
    pff_fused4<<<grid, block, 0, stream>>>(features, inpt, wgt, bias, out);
}

// Round 4
// 79.125 us; speedup vs baseline: 10.2801x; 2.3704x over previous
//
#include <hip/hip_runtime.h>
#include <math.h>

// Problem constants (fixed by setup_inputs)
#define BB 4
#define NI 64
#define CC 64
#define HH 256
#define WW 256
#define HW (HH * WW)

// numpy/jax "reflect" (mirror, edge not repeated), pad=1 so i in [-1, n]
__device__ __forceinline__ int refl(int i, int n) {
    i = (i < 0) ? -i : i;
    return (i >= n) ? (2 * n - 2 - i) : i;
}

// 512 threads/block = 256 pixel slots (64w x 4h) x 2 channel-halves.
// half h: conv partials over ni in [32h,32h+32); LDS combine + redundant
// softmax; then apply filter to channels [32h,32h+32).
// R2 lesson: no launch_bounds reg cap (spill). R3 lesson: half index MUST be
// scalarized (readfirstlane) or all weight loads become per-lane vector loads.
__global__ __launch_bounds__(512) void pff_fused2b(
    const float* __restrict__ features,
    const float* __restrict__ inpt,
    const float* __restrict__ wgt,
    const float* __restrict__ bias,
    float* __restrict__ out)
{
    __shared__ float part[2][9][256];    // 18 KB; stride-1 in pixel slot

    const int tid  = threadIdx.x;
    // wave-uniform by construction (waves 0-3 -> 0, waves 4-7 -> 1);
    // readfirstlane makes the compiler SEE it as uniform -> weights via s_load
    const int half = __builtin_amdgcn_readfirstlane(tid >> 8);
    const int p    = tid & 255;
    const int wx = blockIdx.x * 64 + (p & 63);   // W: 4 strips of 64
    const int hy = blockIdx.y * 4 + (p >> 6);    // H: 64 groups of 4
    const int b  = blockIdx.z;

    const int r0 = refl(hy - 1, HH) * WW;
    const int r1 = hy * WW;
    const int r2 = refl(hy + 1, HH) * WW;
    const int iw0 = refl(wx - 1, WW), iw1 = wx, iw2 = refl(wx + 1, WW);

    float acc[9];
    #pragma unroll
    for (int k = 0; k < 9; ++k) acc[k] = 0.f;

    // ---- Phase 1: conv partials over this half's 32 channels ----
    const float* fb = features + (size_t)b * NI * HW + (size_t)half * 32 * HW;
    for (int ni = 0; ni < 32; ++ni) {
        const float* fc = fb + (size_t)ni * HW;
        float f0 = fc[r0 + iw0], f1 = fc[r0 + iw1], f2 = fc[r0 + iw2];
        float f3 = fc[r1 + iw0], f4 = fc[r1 + iw1], f5 = fc[r1 + iw2];
        float f6 = fc[r2 + iw0], f7 = fc[r2 + iw1], f8 = fc[r2 + iw2];
        // scalar (wave-uniform) weight base: s_load stream, off the VALU
        const float* wn = wgt + (half * 32 + ni) * 9;   // wgt[9][NI][3][3]
        #pragma unroll
        for (int k = 0; k < 9; ++k) {
            const float* wk = wn + k * (NI * 9);
            acc[k] = fmaf(f0, wk[0], acc[k]);
            acc[k] = fmaf(f1, wk[1], acc[k]);
            acc[k] = fmaf(f2, wk[2], acc[k]);
            acc[k] = fmaf(f3, wk[3], acc[k]);
            acc[k] = fmaf(f4, wk[4], acc[k]);
            acc[k] = fmaf(f5, wk[5], acc[k]);
            acc[k] = fmaf(f6, wk[6], acc[k]);
            acc[k] = fmaf(f7, wk[7], acc[k]);
            acc[k] = fmaf(f8, wk[8], acc[k]);
        }
    }

    // ---- combine partials across halves, softmax (redundant per half) ----
    #pragma unroll
    for (int k = 0; k < 9; ++k) part[half][k][p] = acc[k];
    __syncthreads();
    #pragma unroll
    for (int k = 0; k < 9; ++k)
        acc[k] = part[0][k][p] + part[1][k][p] + bias[k];

    float m = acc[0];
    #pragma unroll
    for (int k = 1; k < 9; ++k) m = fmaxf(m, acc[k]);
    float s = 0.f;
    #pragma unroll
    for (int k = 0; k < 9; ++k) { acc[k] = __expf(acc[k] - m); s += acc[k]; }
    const float inv = 1.f / s;
    #pragma unroll
    for (int k = 0; k < 9; ++k) acc[k] *= inv;

    // ---- Phase 2: apply filter to this half's 32 channels ----
    const float* ib = inpt + (size_t)b * CC * HW + (size_t)half * 32 * HW;
    float* ob       = out  + (size_t)b * CC * HW + (size_t)half * 32 * HW;
    const int opix = r1 + wx;
    for (int c = 0; c < 32; ++c) {
        const float* ic = ib + (size_t)c * HW;
        float o = acc[0] * ic[r0 + iw0];
        o = fmaf(acc[1], ic[r0 + iw1], o);
        o = fmaf(acc[2], ic[r0 + iw2], o);
        o = fmaf(acc[3], ic[r1 + iw0], o);
        o = fmaf(acc[4], ic[r1 + iw1], o);
        o = fmaf(acc[5], ic[r1 + iw2], o);
        o = fmaf(acc[6], ic[r2 + iw0], o);
        o = fmaf(acc[7], ic[r2 + iw1], o);
        o = fmaf(acc[8], ic[r2 + iw2], o);
        ob[(size_t)c * HW + opix] = o;
    }
}

extern "C" void kernel_launch(void* const* d_in, const int* in_sizes, int n_in,
                              void* d_out, int out_size, void* d_ws, size_t ws_size,
                              hipStream_t stream) {
    const float* features = (const float*)d_in[0];
    const float* inpt     = (const float*)d_in[1];
    const float* wgt      = (const float*)d_in[2];
    const float* bias     = (const float*)d_in[3];
    float* out            = (float*)d_out;

    dim3 grid(WW / 64, HH / 4, BB);   // (4, 64, 4) = 1024 blocks, 8192 waves
    dim3 block(512);
    pff_fused2b<<<grid, block, 0, stream>>>(features, inpt, wgt, bias, out);
}